// Round 1
// baseline (96.899 us; speedup 1.0000x reference)
//
#include <hip/hip_runtime.h>

#define B_ 4
#define C_ 64
#define H_ 96
#define W_ 96
#define KS_ 7
#define PH_ 102      // padded spatial extent
#define PSTR 104     // padded row stride (floats), keeps 16-aligned w0 float4-legal

// ws layout (floats):
//   q: [B][C][96][96]      = 2359296
//   k: [B][C][102][104]    = 2715648
//   v: [B][C][102][104]    = 2715648

__global__ __launch_bounds__(256) void qkv_conv_kernel(
    const float* __restrict__ in,
    const float* __restrict__ qw, const float* __restrict__ qb,
    const float* __restrict__ kw, const float* __restrict__ kb,
    const float* __restrict__ vw, const float* __restrict__ vb,
    float* __restrict__ outq, float* __restrict__ outk, float* __restrict__ outv)
{
    const int mode = blockIdx.z;   // 0=q, 1=k, 2=v
    const int b = blockIdx.y;
    const int p = blockIdx.x * 256 + threadIdx.x;

    int h, wc, ph = 0, pw = 0;
    bool inb = true;
    const float* w;
    const float* bi;
    if (mode == 0) {
        if (p >= H_ * W_) return;
        h = p / W_; wc = p - h * W_;
        w = qw; bi = qb;
    } else {
        if (p >= PH_ * PH_) return;
        ph = p / PH_; pw = p - ph * PH_;
        h = ph - 3; wc = pw - 3;
        inb = (h >= 0 && h < H_ && wc >= 0 && wc < W_);
        w  = (mode == 1) ? kw : vw;
        bi = (mode == 1) ? kb : vb;
    }

    float x[C_];
    if (inb) {
        const float* ip = in + ((size_t)b * C_ * H_ + h) * W_ + wc;
        #pragma unroll
        for (int c = 0; c < C_; ++c) x[c] = ip[(size_t)c * H_ * W_];
    } else {
        #pragma unroll
        for (int c = 0; c < C_; ++c) x[c] = 0.f;
    }

    if (mode == 0) {
        float* op = outq + ((size_t)b * C_ * H_ + h) * W_ + wc;
        #pragma unroll 1
        for (int o = 0; o < C_; ++o) {
            float acc = bi[o];
            #pragma unroll
            for (int c = 0; c < C_; ++c) acc = fmaf(w[o * C_ + c], x[c], acc);
            op[(size_t)o * H_ * W_] = acc;
        }
    } else {
        float* op = ((mode == 1) ? outk : outv) + ((size_t)b * C_ * PH_ + ph) * PSTR + pw;
        #pragma unroll 1
        for (int o = 0; o < C_; ++o) {
            float acc = bi[o];
            #pragma unroll
            for (int c = 0; c < C_; ++c) acc = fmaf(w[o * C_ + c], x[c], acc);
            op[(size_t)o * PH_ * PSTR] = acc;
        }
    }
}

__global__ __launch_bounds__(256) void attn_kernel(
    const float* __restrict__ q, const float* __restrict__ k,
    const float* __restrict__ v, const float* __restrict__ relh,
    const float* __restrict__ relw, float* __restrict__ out)
{
    // unit = ((b*64 + c)*96 + ho)*6 + w0b ; 147456 units total
    const int u = blockIdx.x * 256 + threadIdx.x;
    const int w0b = u % 6;
    int t1 = u / 6;
    const int ho = t1 % H_;
    int t2 = t1 / H_;
    const int c = t2 % C_;
    const int b = t2 / C_;
    const int w0 = w0b * 16;

    // rel reductions (wave-uniform -> scalar loads, K$-cached)
    float sh[KS_], sw[KS_];
    #pragma unroll
    for (int i = 0; i < KS_; ++i) {
        float s = 0.f;
        #pragma unroll
        for (int cc = 0; cc < 32; ++cc) s += relh[cc * KS_ + i];
        sh[i] = s;
    }
    #pragma unroll
    for (int j = 0; j < KS_; ++j) {
        float s = 0.f;
        #pragma unroll
        for (int cc = 0; cc < 32; ++cc) s += relw[cc * KS_ + j];
        sw[j] = s;
    }

    const float* qp = q + (((size_t)b * C_ + c) * H_ + ho) * W_ + w0;
    float qs[16];
    #pragma unroll
    for (int t = 0; t < 16; t += 4) {
        float4 f = *reinterpret_cast<const float4*>(qp + t);
        qs[t] = f.x; qs[t + 1] = f.y; qs[t + 2] = f.z; qs[t + 3] = f.w;
    }
    float qsum = 0.f;
    #pragma unroll
    for (int t = 0; t < 16; ++t) qsum += qs[t];

    const float* kp0 = k + ((size_t)b * C_ + c) * PH_ * PSTR + (size_t)ho * PSTR + w0;
    float logit[49];
    #pragma unroll
    for (int i = 0; i < KS_; ++i) {
        float kr[22];
        const float* kp = kp0 + i * PSTR;
        #pragma unroll
        for (int t = 0; t < 20; t += 4) {
            float4 f = *reinterpret_cast<const float4*>(kp + t);
            kr[t] = f.x; kr[t + 1] = f.y; kr[t + 2] = f.z; kr[t + 3] = f.w;
        }
        float2 f2 = *reinterpret_cast<const float2*>(kp + 20);
        kr[20] = f2.x; kr[21] = f2.y;
        #pragma unroll
        for (int j = 0; j < KS_; ++j) {
            float s = 0.f;
            #pragma unroll
            for (int t = 0; t < 16; ++t) s = fmaf(qs[t], kr[t + j], s);
            logit[i * KS_ + j] = s + qsum * (sh[i] + sw[j]);
        }
    }

    // softmax over 49
    float m = -1e30f;
    #pragma unroll
    for (int kk = 0; kk < 49; ++kk) m = fmaxf(m, logit[kk]);
    float ssum = 0.f;
    #pragma unroll
    for (int kk = 0; kk < 49; ++kk) {
        float e = __expf(logit[kk] - m);
        logit[kk] = e;
        ssum += e;
    }
    const float inv = 1.f / ssum;

    float o16[16];
    #pragma unroll
    for (int d = 0; d < 16; ++d) o16[d] = 0.f;

    const float* vp0 = v + ((size_t)b * C_ + c) * PH_ * PSTR + (size_t)ho * PSTR + w0;
    #pragma unroll
    for (int i = 0; i < KS_; ++i) {
        float vr[22];
        const float* vp = vp0 + i * PSTR;
        #pragma unroll
        for (int t = 0; t < 20; t += 4) {
            float4 f = *reinterpret_cast<const float4*>(vp + t);
            vr[t] = f.x; vr[t + 1] = f.y; vr[t + 2] = f.z; vr[t + 3] = f.w;
        }
        float2 f2 = *reinterpret_cast<const float2*>(vp + 20);
        vr[20] = f2.x; vr[21] = f2.y;
        #pragma unroll
        for (int j = 0; j < KS_; ++j) {
            float wgt = logit[i * KS_ + j];
            #pragma unroll
            for (int d = 0; d < 16; ++d) o16[d] = fmaf(wgt, vr[d + j], o16[d]);
        }
    }

    float* op = out + (((size_t)b * C_ + c) * H_ + ho) * W_ + w0;
    #pragma unroll
    for (int d = 0; d < 16; d += 4) {
        float4 f;
        f.x = fmaxf(o16[d]     * inv, 0.f);
        f.y = fmaxf(o16[d + 1] * inv, 0.f);
        f.z = fmaxf(o16[d + 2] * inv, 0.f);
        f.w = fmaxf(o16[d + 3] * inv, 0.f);
        *reinterpret_cast<float4*>(op + d) = f;
    }
}

extern "C" void kernel_launch(void* const* d_in, const int* in_sizes, int n_in,
                              void* d_out, int out_size, void* d_ws, size_t ws_size,
                              hipStream_t stream) {
    const float* in   = (const float*)d_in[0];
    const float* qw   = (const float*)d_in[1];
    const float* qb   = (const float*)d_in[2];
    const float* kw   = (const float*)d_in[3];
    const float* kb   = (const float*)d_in[4];
    const float* vw   = (const float*)d_in[5];
    const float* vb   = (const float*)d_in[6];
    const float* relh = (const float*)d_in[7];
    const float* relw = (const float*)d_in[8];
    float* out = (float*)d_out;

    float* wq = (float*)d_ws;
    float* wk = wq + (size_t)B_ * C_ * H_ * W_;
    float* wv = wk + (size_t)B_ * C_ * PH_ * PSTR;

    dim3 cgrid((PH_ * PH_ + 255) / 256, B_, 3);
    qkv_conv_kernel<<<cgrid, 256, 0, stream>>>(in, qw, qb, kw, kb, vw, vb, wq, wk, wv);

    dim3 agrid((B_ * C_ * H_ * 6) / 256);  // 576 blocks
    attn_kernel<<<agrid, 256, 0, stream>>>(wq, wk, wv, relh, relw, out);
}

// Round 2
// 72.580 us; speedup vs baseline: 1.3351x; 1.3351x over previous
//
#include <hip/hip_runtime.h>

#define B_ 4
#define C_ 64
#define H_ 96
#define W_ 96
#define KS_ 7
#define PH_ 102      // padded spatial extent
#define PSTR 104     // padded row stride (floats), keeps 16-aligned w0 float4-legal

// ws layout (floats):
//   k:   [B][C][102][104]  = 2715648
//   v:   [B][C][102][104]  = 2715648
//   rel: [49]
// q lives in d_out (same shape as output; overwritten by attn afterwards).

__global__ void rel_kernel(const float* __restrict__ relh,
                           const float* __restrict__ relw,
                           float* __restrict__ rel)
{
    const int kk = threadIdx.x;
    if (kk < KS_ * KS_) {
        const int i = kk / KS_, j = kk % KS_;
        float s = 0.f;
        #pragma unroll
        for (int cc = 0; cc < C_ / 2; ++cc)
            s += relh[cc * KS_ + i] + relw[cc * KS_ + j];
        rel[kk] = s;
    }
}

__global__ __launch_bounds__(256) void qkv_conv_kernel(
    const float* __restrict__ in,
    const float* __restrict__ qw, const float* __restrict__ qb,
    const float* __restrict__ kw, const float* __restrict__ kb,
    const float* __restrict__ vw, const float* __restrict__ vb,
    float* __restrict__ outq, float* __restrict__ outk, float* __restrict__ outv)
{
    const int mz   = blockIdx.z;       // mode*4 + ob16
    const int mode = mz >> 2;
    const int ob   = (mz & 3) * 16;    // output-channel base
    const int b    = blockIdx.y;
    const int p    = blockIdx.x * 256 + threadIdx.x;

    int h, wc, ph = 0, pw = 0;
    bool inb = true;
    const float* w;
    const float* bi;
    if (mode == 0) {
        if (p >= H_ * W_) return;
        h = p / W_; wc = p - h * W_;
        w = qw; bi = qb;
    } else {
        if (p >= PH_ * PH_) return;
        ph = p / PH_; pw = p - ph * PH_;
        h = ph - 3; wc = pw - 3;
        inb = (h >= 0 && h < H_ && wc >= 0 && wc < W_);
        w  = (mode == 1) ? kw : vw;
        bi = (mode == 1) ? kb : vb;
    }

    float acc[16];
    #pragma unroll
    for (int t = 0; t < 16; ++t) acc[t] = bi[ob + t];

    if (inb) {
        const float* ip = in + (size_t)b * C_ * H_ * W_ + (size_t)h * W_ + wc;
        #pragma unroll
        for (int c0 = 0; c0 < C_; c0 += 8) {
            float x[8];
            #pragma unroll
            for (int cc = 0; cc < 8; ++cc) x[cc] = ip[(size_t)(c0 + cc) * H_ * W_];
            #pragma unroll
            for (int t = 0; t < 16; ++t) {
                #pragma unroll
                for (int cc = 0; cc < 8; ++cc)
                    acc[t] = fmaf(w[(ob + t) * C_ + c0 + cc], x[cc], acc[t]);
            }
        }
    }

    if (mode == 0) {
        float* op = outq + ((size_t)b * C_ + ob) * H_ * W_ + (size_t)h * W_ + wc;
        #pragma unroll
        for (int t = 0; t < 16; ++t) op[(size_t)t * H_ * W_] = acc[t];
    } else {
        float* op = ((mode == 1) ? outk : outv)
                  + ((size_t)b * C_ + ob) * PH_ * PSTR + (size_t)ph * PSTR + pw;
        #pragma unroll
        for (int t = 0; t < 16; ++t) op[(size_t)t * PH_ * PSTR] = acc[t];
    }
}

__global__ __launch_bounds__(256) void attn_kernel(
    const float* __restrict__ q, const float* __restrict__ k,
    const float* __restrict__ v, const float* __restrict__ rel,
    float* __restrict__ out)
{
    // u = (((b*64 + c)*96 + ho)*6 + w0b)*2 + half ; 294912 threads
    const int u   = blockIdx.x * 256 + threadIdx.x;
    const int hw  = u % 12;
    const int w0b = hw >> 1;
    const int half = hw & 1;
    int t1 = u / 12;
    const int ho = t1 % H_;
    int t2 = t1 / H_;
    const int c = t2 % C_;
    const int b = t2 / C_;
    const int w0 = w0b * 16;

    const float* qp = q + (((size_t)b * C_ + c) * H_ + ho) * W_ + w0;
    float qs[16];
    #pragma unroll
    for (int t = 0; t < 16; t += 4) {
        float4 f = *reinterpret_cast<const float4*>(qp + t);
        qs[t] = f.x; qs[t + 1] = f.y; qs[t + 2] = f.z; qs[t + 3] = f.w;
    }
    float qsum = 0.f;
    #pragma unroll
    for (int t = 0; t < 16; ++t) qsum += qs[t];

    const float* kp0 = k + ((size_t)b * C_ + c) * PH_ * PSTR + (size_t)ho * PSTR + w0;
    float logit[49];
    #pragma unroll
    for (int i = 0; i < KS_; ++i) {
        float kr[22];
        const float* kp = kp0 + i * PSTR;
        #pragma unroll
        for (int t = 0; t < 20; t += 4) {
            float4 f = *reinterpret_cast<const float4*>(kp + t);
            kr[t] = f.x; kr[t + 1] = f.y; kr[t + 2] = f.z; kr[t + 3] = f.w;
        }
        float2 f2 = *reinterpret_cast<const float2*>(kp + 20);
        kr[20] = f2.x; kr[21] = f2.y;
        #pragma unroll
        for (int j = 0; j < KS_; ++j) {
            float s = 0.f;
            #pragma unroll
            for (int t = 0; t < 16; ++t) s = fmaf(qs[t], kr[t + j], s);
            logit[i * KS_ + j] = s + qsum * rel[i * KS_ + j];
        }
    }

    // softmax over 49
    float m = -1e30f;
    #pragma unroll
    for (int kk = 0; kk < 49; ++kk) m = fmaxf(m, logit[kk]);
    float ssum = 0.f;
    #pragma unroll
    for (int kk = 0; kk < 49; ++kk) {
        float e = __expf(logit[kk] - m);
        logit[kk] = e;
        ssum += e;
    }
    const float inv = 1.f / ssum;

    // PV for d = half*8 .. half*8+7
    float o8[8];
    #pragma unroll
    for (int d = 0; d < 8; ++d) o8[d] = 0.f;

    const float* vp0 = v + ((size_t)b * C_ + c) * PH_ * PSTR + (size_t)ho * PSTR
                     + w0 + half * 8;
    #pragma unroll
    for (int i = 0; i < KS_; ++i) {
        float vr[14];
        const float* vp = vp0 + i * PSTR;
        #pragma unroll
        for (int t = 0; t < 12; t += 4) {
            float4 f = *reinterpret_cast<const float4*>(vp + t);
            vr[t] = f.x; vr[t + 1] = f.y; vr[t + 2] = f.z; vr[t + 3] = f.w;
        }
        float2 f2 = *reinterpret_cast<const float2*>(vp + 12);
        vr[12] = f2.x; vr[13] = f2.y;
        #pragma unroll
        for (int j = 0; j < KS_; ++j) {
            float wgt = logit[i * KS_ + j];
            #pragma unroll
            for (int d = 0; d < 8; ++d) o8[d] = fmaf(wgt, vr[d + j], o8[d]);
        }
    }

    float* op = out + (((size_t)b * C_ + c) * H_ + ho) * W_ + w0 + half * 8;
    #pragma unroll
    for (int d = 0; d < 8; d += 4) {
        float4 f;
        f.x = fmaxf(o8[d]     * inv, 0.f);
        f.y = fmaxf(o8[d + 1] * inv, 0.f);
        f.z = fmaxf(o8[d + 2] * inv, 0.f);
        f.w = fmaxf(o8[d + 3] * inv, 0.f);
        *reinterpret_cast<float4*>(op + d) = f;
    }
}

extern "C" void kernel_launch(void* const* d_in, const int* in_sizes, int n_in,
                              void* d_out, int out_size, void* d_ws, size_t ws_size,
                              hipStream_t stream) {
    const float* in   = (const float*)d_in[0];
    const float* qw   = (const float*)d_in[1];
    const float* qb   = (const float*)d_in[2];
    const float* kw   = (const float*)d_in[3];
    const float* kb   = (const float*)d_in[4];
    const float* vw   = (const float*)d_in[5];
    const float* vb   = (const float*)d_in[6];
    const float* relh = (const float*)d_in[7];
    const float* relw = (const float*)d_in[8];
    float* out = (float*)d_out;

    float* wk   = (float*)d_ws;
    float* wv   = wk + (size_t)B_ * C_ * PH_ * PSTR;
    float* wrel = wv + (size_t)B_ * C_ * PH_ * PSTR;
    float* wq   = out;   // q staged in d_out; overwritten by attn afterwards

    rel_kernel<<<1, 64, 0, stream>>>(relh, relw, wrel);

    dim3 cgrid((PH_ * PH_ + 255) / 256, B_, 12);
    qkv_conv_kernel<<<cgrid, 256, 0, stream>>>(in, qw, qb, kw, kb, vw, vb, wq, wk, wv);

    dim3 agrid((B_ * C_ * H_ * 12) / 256);  // 1152 blocks
    attn_kernel<<<agrid, 256, 0, stream>>>(wq, wk, wv, wrel, out);
}

// Round 3
// 60.359 us; speedup vs baseline: 1.6054x; 1.2025x over previous
//
#include <hip/hip_runtime.h>

#define B_ 4
#define C_ 64
#define H_ 96
#define W_ 96
#define KS_ 7
#define PH_ 102      // padded spatial extent
#define PSTR 104     // padded row stride (floats), keeps 16-aligned w0 float4-legal

// ws layout (floats):
//   k:   [B][C][102][104]  = 2715648
//   v:   [B][C][102][104]  = 2715648
//   q:   [B][C][96][96]    = 2359296
//   rel: [49]

__global__ void rel_kernel(const float* __restrict__ relh,
                           const float* __restrict__ relw,
                           float* __restrict__ rel)
{
    const int kk = threadIdx.x;
    if (kk < KS_ * KS_) {
        const int i = kk / KS_, j = kk % KS_;
        float s = 0.f;
        #pragma unroll
        for (int cc = 0; cc < C_ / 2; ++cc)
            s += relh[cc * KS_ + i] + relw[cc * KS_ + j];
        rel[kk] = s;
    }
}

// thread = 1 pixel, all 64 output channels; x[64] hoisted to VGPR once,
// 8 rounds of 8 accumulators x 64 K fully-unrolled FMAs (weights via s_load).
__global__ __launch_bounds__(128) void qkv_conv_kernel(
    const float* __restrict__ in,
    const float* __restrict__ qw, const float* __restrict__ qb,
    const float* __restrict__ kw, const float* __restrict__ kb,
    const float* __restrict__ vw, const float* __restrict__ vb,
    float* __restrict__ outq, float* __restrict__ outk, float* __restrict__ outv)
{
    const int mode = blockIdx.z;   // 0=q, 1=k, 2=v
    const int b    = blockIdx.y;
    const int p    = blockIdx.x * 128 + threadIdx.x;

    int h, wc;
    bool inb;
    const float* w;
    const float* bi;
    float* op;
    size_t ostr;

    if (mode == 0) {
        if (p >= H_ * W_) return;
        h = p / W_; wc = p - h * W_;
        inb = true;
        w = qw; bi = qb;
        op = outq + (size_t)b * C_ * H_ * W_ + (size_t)h * W_ + wc;
        ostr = (size_t)H_ * W_;
    } else {
        if (p >= PH_ * PH_) return;
        const int ph = p / PH_, pw = p - ph * PH_;
        h = ph - 3; wc = pw - 3;
        inb = (h >= 0 && h < H_ && wc >= 0 && wc < W_);
        w  = (mode == 1) ? kw : vw;
        bi = (mode == 1) ? kb : vb;
        op = ((mode == 1) ? outk : outv)
           + (size_t)b * C_ * PH_ * PSTR + (size_t)ph * PSTR + pw;
        ostr = (size_t)PH_ * PSTR;
    }

    // hoist the entire input-channel vector into VGPRs (one latency exposure)
    float x[C_];
    if (inb) {
        const float* ip = in + (size_t)b * C_ * H_ * W_ + (size_t)h * W_ + wc;
        #pragma unroll
        for (int c = 0; c < C_; ++c) x[c] = ip[(size_t)c * H_ * W_];
    } else {
        #pragma unroll
        for (int c = 0; c < C_; ++c) x[c] = 0.f;
    }

    #pragma unroll 1
    for (int r = 0; r < 8; ++r) {
        const int ob = r * 8;
        float acc[8];
        #pragma unroll
        for (int t = 0; t < 8; ++t) acc[t] = bi[ob + t];
        #pragma unroll
        for (int c = 0; c < C_; ++c) {
            #pragma unroll
            for (int t = 0; t < 8; ++t)
                acc[t] = fmaf(w[(ob + t) * C_ + c], x[c], acc[t]);
        }
        #pragma unroll
        for (int t = 0; t < 8; ++t) op[(size_t)(ob + t) * ostr] = acc[t];
    }
}

__global__ __launch_bounds__(256) void attn_kernel(
    const float* __restrict__ q, const float* __restrict__ k,
    const float* __restrict__ v, const float* __restrict__ rel,
    float* __restrict__ out)
{
    // u = (((b*64 + c)*96 + ho)*6 + w0b)*2 + half ; 294912 threads
    const int u   = blockIdx.x * 256 + threadIdx.x;
    const int hw  = u % 12;
    const int w0b = hw >> 1;
    const int half = hw & 1;
    int t1 = u / 12;
    const int ho = t1 % H_;
    int t2 = t1 / H_;
    const int c = t2 % C_;
    const int b = t2 / C_;
    const int w0 = w0b * 16;

    const float* qp = q + (((size_t)b * C_ + c) * H_ + ho) * W_ + w0;
    float qs[16];
    #pragma unroll
    for (int t = 0; t < 16; t += 4) {
        float4 f = *reinterpret_cast<const float4*>(qp + t);
        qs[t] = f.x; qs[t + 1] = f.y; qs[t + 2] = f.z; qs[t + 3] = f.w;
    }
    float qsum = 0.f;
    #pragma unroll
    for (int t = 0; t < 16; ++t) qsum += qs[t];

    const float* kp0 = k + ((size_t)b * C_ + c) * PH_ * PSTR + (size_t)ho * PSTR + w0;
    float logit[49];
    #pragma unroll
    for (int i = 0; i < KS_; ++i) {
        float kr[22];
        const float* kp = kp0 + i * PSTR;
        #pragma unroll
        for (int t = 0; t < 20; t += 4) {
            float4 f = *reinterpret_cast<const float4*>(kp + t);
            kr[t] = f.x; kr[t + 1] = f.y; kr[t + 2] = f.z; kr[t + 3] = f.w;
        }
        float2 f2 = *reinterpret_cast<const float2*>(kp + 20);
        kr[20] = f2.x; kr[21] = f2.y;
        #pragma unroll
        for (int j = 0; j < KS_; ++j) {
            float s = 0.f;
            #pragma unroll
            for (int t = 0; t < 16; ++t) s = fmaf(qs[t], kr[t + j], s);
            logit[i * KS_ + j] = s + qsum * rel[i * KS_ + j];
        }
    }

    // softmax over 49
    float m = -1e30f;
    #pragma unroll
    for (int kk = 0; kk < 49; ++kk) m = fmaxf(m, logit[kk]);
    float ssum = 0.f;
    #pragma unroll
    for (int kk = 0; kk < 49; ++kk) {
        float e = __expf(logit[kk] - m);
        logit[kk] = e;
        ssum += e;
    }
    const float inv = 1.f / ssum;

    // PV for d = half*8 .. half*8+7
    float o8[8];
    #pragma unroll
    for (int d = 0; d < 8; ++d) o8[d] = 0.f;

    const float* vp0 = v + ((size_t)b * C_ + c) * PH_ * PSTR + (size_t)ho * PSTR
                     + w0 + half * 8;
    #pragma unroll
    for (int i = 0; i < KS_; ++i) {
        float vr[14];
        const float* vp = vp0 + i * PSTR;
        #pragma unroll
        for (int t = 0; t < 12; t += 4) {
            float4 f = *reinterpret_cast<const float4*>(vp + t);
            vr[t] = f.x; vr[t + 1] = f.y; vr[t + 2] = f.z; vr[t + 3] = f.w;
        }
        float2 f2 = *reinterpret_cast<const float2*>(vp + 12);
        vr[12] = f2.x; vr[13] = f2.y;
        #pragma unroll
        for (int j = 0; j < KS_; ++j) {
            float wgt = logit[i * KS_ + j];
            #pragma unroll
            for (int d = 0; d < 8; ++d) o8[d] = fmaf(wgt, vr[d + j], o8[d]);
        }
    }

    float* op = out + (((size_t)b * C_ + c) * H_ + ho) * W_ + w0 + half * 8;
    #pragma unroll
    for (int d = 0; d < 8; d += 4) {
        float4 f;
        f.x = fmaxf(o8[d]     * inv, 0.f);
        f.y = fmaxf(o8[d + 1] * inv, 0.f);
        f.z = fmaxf(o8[d + 2] * inv, 0.f);
        f.w = fmaxf(o8[d + 3] * inv, 0.f);
        *reinterpret_cast<float4*>(op + d) = f;
    }
}

extern "C" void kernel_launch(void* const* d_in, const int* in_sizes, int n_in,
                              void* d_out, int out_size, void* d_ws, size_t ws_size,
                              hipStream_t stream) {
    const float* in   = (const float*)d_in[0];
    const float* qw   = (const float*)d_in[1];
    const float* qb   = (const float*)d_in[2];
    const float* kw   = (const float*)d_in[3];
    const float* kb   = (const float*)d_in[4];
    const float* vw   = (const float*)d_in[5];
    const float* vb   = (const float*)d_in[6];
    const float* relh = (const float*)d_in[7];
    const float* relw = (const float*)d_in[8];
    float* out = (float*)d_out;

    float* wk   = (float*)d_ws;
    float* wv   = wk + (size_t)B_ * C_ * PH_ * PSTR;
    float* wq   = wv + (size_t)B_ * C_ * PH_ * PSTR;
    float* wrel = wq + (size_t)B_ * C_ * H_ * W_;

    rel_kernel<<<1, 64, 0, stream>>>(relh, relw, wrel);

    dim3 cgrid((PH_ * PH_ + 127) / 128, B_, 3);   // 82 x 4 x 3 = 984 blocks
    qkv_conv_kernel<<<cgrid, 128, 0, stream>>>(in, qw, qb, kw, kb, vw, vb, wq, wk, wv);

    dim3 agrid((B_ * C_ * H_ * 12) / 256);  // 1152 blocks
    attn_kernel<<<agrid, 256, 0, stream>>>(wq, wk, wv, wrel, out);
}

// Round 4
// 47.697 us; speedup vs baseline: 2.0316x; 1.2655x over previous
//
#include <hip/hip_runtime.h>

#define B_ 4
#define C_ 64
#define H_ 96
#define W_ 96
#define KS_ 7
#define PH_ 102      // padded spatial extent
#define PSTR 104     // padded row stride (floats), keeps 16-aligned w0 float4-legal
#define LDSTR 108    // LDS row stride: 16B-aligned, bank-stride 12 breaks aliasing

// ws layout (floats):
//   k: [B][C][102][104]  = 2715648
//   v: [B][C][102][104]  = 2715648
//   q: [B][C][96][96]    = 2359296

// thread = 1 pixel, 32 of 64 output channels (z-split); x[64] hoisted to VGPR
// once, 4 rounds of 8 accumulators x 64 K fully-unrolled FMAs (s_load weights).
__global__ __launch_bounds__(128) void qkv_conv_kernel(
    const float* __restrict__ in,
    const float* __restrict__ qw, const float* __restrict__ qb,
    const float* __restrict__ kw, const float* __restrict__ kb,
    const float* __restrict__ vw, const float* __restrict__ vb,
    float* __restrict__ outq, float* __restrict__ outk, float* __restrict__ outv)
{
    const int mz   = blockIdx.z;
    const int mode = mz >> 1;          // 0=q, 1=k, 2=v
    const int obase = (mz & 1) * 32;   // output-channel half
    const int b    = blockIdx.y;
    const int p    = blockIdx.x * 128 + threadIdx.x;

    int h, wc;
    bool inb;
    const float* w;
    const float* bi;
    float* op;
    size_t ostr;

    if (mode == 0) {
        if (p >= H_ * W_) return;
        h = p / W_; wc = p - h * W_;
        inb = true;
        w = qw; bi = qb;
        op = outq + ((size_t)b * C_ + obase) * H_ * W_ + (size_t)h * W_ + wc;
        ostr = (size_t)H_ * W_;
    } else {
        if (p >= PH_ * PH_) return;
        const int ph = p / PH_, pw = p - ph * PH_;
        h = ph - 3; wc = pw - 3;
        inb = (h >= 0 && h < H_ && wc >= 0 && wc < W_);
        w  = (mode == 1) ? kw : vw;
        bi = (mode == 1) ? kb : vb;
        op = ((mode == 1) ? outk : outv)
           + ((size_t)b * C_ + obase) * PH_ * PSTR + (size_t)ph * PSTR + pw;
        ostr = (size_t)PH_ * PSTR;
    }

    // hoist the entire input-channel vector into VGPRs (one latency exposure)
    float x[C_];
    if (inb) {
        const float* ip = in + (size_t)b * C_ * H_ * W_ + (size_t)h * W_ + wc;
        #pragma unroll
        for (int c = 0; c < C_; ++c) x[c] = ip[(size_t)c * H_ * W_];
    } else {
        #pragma unroll
        for (int c = 0; c < C_; ++c) x[c] = 0.f;
    }

    #pragma unroll 1
    for (int r = 0; r < 4; ++r) {
        const int ob = obase + r * 8;
        float acc[8];
        #pragma unroll
        for (int t = 0; t < 8; ++t) acc[t] = bi[ob + t];
        #pragma unroll
        for (int c = 0; c < C_; ++c) {
            #pragma unroll
            for (int t = 0; t < 8; ++t)
                acc[t] = fmaf(w[(ob + t) * C_ + c], x[c], acc[t]);
        }
        #pragma unroll
        for (int t = 0; t < 8; ++t) op[(size_t)(r * 8 + t) * ostr] = acc[t];
    }
}

// block = (b, c, 32-row tile): stage k/v slab (38 x 104 -> LDS stride 108),
// thread = one softmax unit (ho, w0), full 16-d output.
__global__ __launch_bounds__(192) void attn_kernel(
    const float* __restrict__ q, const float* __restrict__ k,
    const float* __restrict__ v, const float* __restrict__ relh,
    const float* __restrict__ relw, float* __restrict__ out)
{
    const int bx   = blockIdx.x;          // ((b*C + c)*3 + tile)
    const int tile = bx % 3;
    const int c    = (bx / 3) % C_;
    const int b    = bx / (3 * C_);
    const int ho0  = tile * 32;
    const int t    = threadIdx.x;

    __shared__ float ks[38 * LDSTR];
    __shared__ float vs[38 * LDSTR];
    __shared__ float rel_s[49];

    if (t < 49) {
        const int i = t / KS_, j = t % KS_;
        float s = 0.f;
        #pragma unroll
        for (int cc = 0; cc < C_ / 2; ++cc)
            s += relh[cc * KS_ + i] + relw[cc * KS_ + j];
        rel_s[t] = s;
    }

    // stage 38 rows x 104 floats of k and v (rows are contiguous in global)
    {
        const float* kp = k + ((size_t)(b * C_ + c) * PH_ + ho0) * PSTR;
        const float* vp = v + ((size_t)(b * C_ + c) * PH_ + ho0) * PSTR;
        for (int idx = t; idx < 38 * 26; idx += 192) {
            const int r = idx / 26, col = (idx % 26) * 4;
            *reinterpret_cast<float4*>(&ks[r * LDSTR + col]) =
                *reinterpret_cast<const float4*>(kp + r * PSTR + col);
            *reinterpret_cast<float4*>(&vs[r * LDSTR + col]) =
                *reinterpret_cast<const float4*>(vp + r * PSTR + col);
        }
    }
    __syncthreads();

    const int r0 = t / 6;            // 0..31
    const int w0 = (t % 6) * 16;
    const int ho = ho0 + r0;

    const float* qp = q + (((size_t)b * C_ + c) * H_ + ho) * W_ + w0;
    float qs[16];
    #pragma unroll
    for (int tt = 0; tt < 16; tt += 4) {
        float4 f = *reinterpret_cast<const float4*>(qp + tt);
        qs[tt] = f.x; qs[tt + 1] = f.y; qs[tt + 2] = f.z; qs[tt + 3] = f.w;
    }
    float qsum = 0.f;
    #pragma unroll
    for (int tt = 0; tt < 16; ++tt) qsum += qs[tt];

    float logit[49];
    #pragma unroll
    for (int i = 0; i < KS_; ++i) {
        float kr[22];
        const float* kp = &ks[(r0 + i) * LDSTR + w0];
        #pragma unroll
        for (int tt = 0; tt < 20; tt += 4) {
            float4 f = *reinterpret_cast<const float4*>(kp + tt);
            kr[tt] = f.x; kr[tt + 1] = f.y; kr[tt + 2] = f.z; kr[tt + 3] = f.w;
        }
        float2 f2 = *reinterpret_cast<const float2*>(kp + 20);
        kr[20] = f2.x; kr[21] = f2.y;
        #pragma unroll
        for (int j = 0; j < KS_; ++j) {
            float s = 0.f;
            #pragma unroll
            for (int tt = 0; tt < 16; ++tt) s = fmaf(qs[tt], kr[tt + j], s);
            logit[i * KS_ + j] = s + qsum * rel_s[i * KS_ + j];
        }
    }

    // softmax over 49
    float m = -1e30f;
    #pragma unroll
    for (int kk = 0; kk < 49; ++kk) m = fmaxf(m, logit[kk]);
    float ssum = 0.f;
    #pragma unroll
    for (int kk = 0; kk < 49; ++kk) {
        float e = __expf(logit[kk] - m);
        logit[kk] = e;
        ssum += e;
    }
    const float inv = 1.f / ssum;

    float o16[16];
    #pragma unroll
    for (int d = 0; d < 16; ++d) o16[d] = 0.f;

    #pragma unroll
    for (int i = 0; i < KS_; ++i) {
        float vr[22];
        const float* vp = &vs[(r0 + i) * LDSTR + w0];
        #pragma unroll
        for (int tt = 0; tt < 20; tt += 4) {
            float4 f = *reinterpret_cast<const float4*>(vp + tt);
            vr[tt] = f.x; vr[tt + 1] = f.y; vr[tt + 2] = f.z; vr[tt + 3] = f.w;
        }
        float2 f2 = *reinterpret_cast<const float2*>(vp + 20);
        vr[20] = f2.x; vr[21] = f2.y;
        #pragma unroll
        for (int j = 0; j < KS_; ++j) {
            float wgt = logit[i * KS_ + j];
            #pragma unroll
            for (int d = 0; d < 16; ++d) o16[d] = fmaf(wgt, vr[d + j], o16[d]);
        }
    }

    float* op = out + (((size_t)b * C_ + c) * H_ + ho) * W_ + w0;
    #pragma unroll
    for (int d = 0; d < 16; d += 4) {
        float4 f;
        f.x = fmaxf(o16[d]     * inv, 0.f);
        f.y = fmaxf(o16[d + 1] * inv, 0.f);
        f.z = fmaxf(o16[d + 2] * inv, 0.f);
        f.w = fmaxf(o16[d + 3] * inv, 0.f);
        *reinterpret_cast<float4*>(op + d) = f;
    }
}

extern "C" void kernel_launch(void* const* d_in, const int* in_sizes, int n_in,
                              void* d_out, int out_size, void* d_ws, size_t ws_size,
                              hipStream_t stream) {
    const float* in   = (const float*)d_in[0];
    const float* qw   = (const float*)d_in[1];
    const float* qb   = (const float*)d_in[2];
    const float* kw   = (const float*)d_in[3];
    const float* kb   = (const float*)d_in[4];
    const float* vw   = (const float*)d_in[5];
    const float* vb   = (const float*)d_in[6];
    const float* relh = (const float*)d_in[7];
    const float* relw = (const float*)d_in[8];
    float* out = (float*)d_out;

    float* wk = (float*)d_ws;
    float* wv = wk + (size_t)B_ * C_ * PH_ * PSTR;
    float* wq = wv + (size_t)B_ * C_ * PH_ * PSTR;

    dim3 cgrid((PH_ * PH_ + 127) / 128, B_, 6);   // 82 x 4 x 6 = 1968 blocks
    qkv_conv_kernel<<<cgrid, 128, 0, stream>>>(in, qw, qb, kw, kb, vw, vb, wq, wk, wv);

    dim3 agrid(B_ * C_ * 3);                      // 768 blocks x 192 threads
    attn_kernel<<<agrid, 192, 0, stream>>>(wq, wk, wv, relh, relw, out);
}

// Round 5
// 46.593 us; speedup vs baseline: 2.0797x; 1.0237x over previous
//
#include <hip/hip_runtime.h>

#define B_ 4
#define C_ 64
#define H_ 96
#define W_ 96
#define KS_ 7
#define PH_ 102      // padded spatial extent
#define PSTR 104     // padded row stride (floats), keeps 16-aligned w0 float4-legal
#define LDSTR 108    // LDS row stride: 16B-aligned, bank-stride 12 breaks aliasing

// ws layout (floats):
//   k: [B][C][102][104]  = 2715648
//   v: [B][C][102][104]  = 2715648
//   q: [B][C][96][96]    = 2359296

// thread = 1 pixel, 16 of 64 output channels (z = mode*4 + quarter);
// x[64] hoisted to VGPR once, 2 rounds of 8 accumulators x 64 K unrolled.
__global__ __launch_bounds__(128) void qkv_conv_kernel(
    const float* __restrict__ in,
    const float* __restrict__ qw, const float* __restrict__ qb,
    const float* __restrict__ kw, const float* __restrict__ kb,
    const float* __restrict__ vw, const float* __restrict__ vb,
    float* __restrict__ outq, float* __restrict__ outk, float* __restrict__ outv)
{
    const int mz    = blockIdx.z;
    const int mode  = mz >> 2;          // 0=q, 1=k, 2=v
    const int obase = (mz & 3) * 16;    // output-channel quarter
    const int b     = blockIdx.y;
    const int p     = blockIdx.x * 128 + threadIdx.x;

    int h, wc;
    bool inb;
    const float* w;
    const float* bi;
    float* op;
    size_t ostr;

    if (mode == 0) {
        if (p >= H_ * W_) return;
        h = p / W_; wc = p - h * W_;
        inb = true;
        w = qw; bi = qb;
        op = outq + ((size_t)b * C_ + obase) * H_ * W_ + (size_t)h * W_ + wc;
        ostr = (size_t)H_ * W_;
    } else {
        if (p >= PH_ * PH_) return;
        const int ph = p / PH_, pw = p - ph * PH_;
        h = ph - 3; wc = pw - 3;
        inb = (h >= 0 && h < H_ && wc >= 0 && wc < W_);
        w  = (mode == 1) ? kw : vw;
        bi = (mode == 1) ? kb : vb;
        op = ((mode == 1) ? outk : outv)
           + ((size_t)b * C_ + obase) * PH_ * PSTR + (size_t)ph * PSTR + pw;
        ostr = (size_t)PH_ * PSTR;
    }

    // hoist the entire input-channel vector into VGPRs (one latency exposure)
    float x[C_];
    if (inb) {
        const float* ip = in + (size_t)b * C_ * H_ * W_ + (size_t)h * W_ + wc;
        #pragma unroll
        for (int c = 0; c < C_; ++c) x[c] = ip[(size_t)c * H_ * W_];
    } else {
        #pragma unroll
        for (int c = 0; c < C_; ++c) x[c] = 0.f;
    }

    #pragma unroll 1
    for (int r = 0; r < 2; ++r) {
        const int ob = obase + r * 8;
        float acc[8];
        #pragma unroll
        for (int t = 0; t < 8; ++t) acc[t] = bi[ob + t];
        #pragma unroll
        for (int c = 0; c < C_; ++c) {
            #pragma unroll
            for (int t = 0; t < 8; ++t)
                acc[t] = fmaf(w[(ob + t) * C_ + c], x[c], acc[t]);
        }
        #pragma unroll
        for (int t = 0; t < 8; ++t) op[(size_t)(r * 8 + t) * ostr] = acc[t];
    }
}

// block = (b, c, 32-row tile): stage k/v slab (38 x 104 -> LDS stride 108).
// thread = (row, w0, half): full QK + softmax, PV for 8 of 16 outputs.
__global__ __launch_bounds__(384) void attn_kernel(
    const float* __restrict__ q, const float* __restrict__ k,
    const float* __restrict__ v, const float* __restrict__ relh,
    const float* __restrict__ relw, float* __restrict__ out)
{
    const int bx   = blockIdx.x;          // ((b*C + c)*3 + tile)
    const int tile = bx % 3;
    const int c    = (bx / 3) % C_;
    const int b    = bx / (3 * C_);
    const int ho0  = tile * 32;
    const int t    = threadIdx.x;

    __shared__ float ks[38 * LDSTR];
    __shared__ float vs[38 * LDSTR];
    __shared__ float rel_s[49];

    if (t < 49) {
        const int i = t / KS_, j = t % KS_;
        float s = 0.f;
        #pragma unroll
        for (int cc = 0; cc < C_ / 2; ++cc)
            s += relh[cc * KS_ + i] + relw[cc * KS_ + j];
        rel_s[t] = s;
    }

    // stage 38 rows x 104 floats of k and v (rows are contiguous in global)
    {
        const float* kp = k + ((size_t)(b * C_ + c) * PH_ + ho0) * PSTR;
        const float* vp = v + ((size_t)(b * C_ + c) * PH_ + ho0) * PSTR;
        for (int idx = t; idx < 38 * 26; idx += 384) {
            const int r = idx / 26, col = (idx % 26) * 4;
            *reinterpret_cast<float4*>(&ks[r * LDSTR + col]) =
                *reinterpret_cast<const float4*>(kp + r * PSTR + col);
            *reinterpret_cast<float4*>(&vs[r * LDSTR + col]) =
                *reinterpret_cast<const float4*>(vp + r * PSTR + col);
        }
    }
    __syncthreads();

    const int r0   = t / 12;             // 0..31
    const int rest = t % 12;
    const int w0b  = rest >> 1;
    const int half = rest & 1;
    const int w0   = w0b * 16;
    const int ho   = ho0 + r0;

    const float* qp = q + (((size_t)b * C_ + c) * H_ + ho) * W_ + w0;
    float qs[16];
    #pragma unroll
    for (int tt = 0; tt < 16; tt += 4) {
        float4 f = *reinterpret_cast<const float4*>(qp + tt);
        qs[tt] = f.x; qs[tt + 1] = f.y; qs[tt + 2] = f.z; qs[tt + 3] = f.w;
    }
    float qsum = 0.f;
    #pragma unroll
    for (int tt = 0; tt < 16; ++tt) qsum += qs[tt];

    float logit[49];
    #pragma unroll
    for (int i = 0; i < KS_; ++i) {
        float kr[22];
        const float* kp = &ks[(r0 + i) * LDSTR + w0];
        #pragma unroll
        for (int tt = 0; tt < 20; tt += 4) {
            float4 f = *reinterpret_cast<const float4*>(kp + tt);
            kr[tt] = f.x; kr[tt + 1] = f.y; kr[tt + 2] = f.z; kr[tt + 3] = f.w;
        }
        float2 f2 = *reinterpret_cast<const float2*>(kp + 20);
        kr[20] = f2.x; kr[21] = f2.y;
        #pragma unroll
        for (int j = 0; j < KS_; ++j) {
            float s = 0.f;
            #pragma unroll
            for (int tt = 0; tt < 16; ++tt) s = fmaf(qs[tt], kr[tt + j], s);
            logit[i * KS_ + j] = s + qsum * rel_s[i * KS_ + j];
        }
    }

    // softmax over 49
    float m = -1e30f;
    #pragma unroll
    for (int kk = 0; kk < 49; ++kk) m = fmaxf(m, logit[kk]);
    float ssum = 0.f;
    #pragma unroll
    for (int kk = 0; kk < 49; ++kk) {
        float e = __expf(logit[kk] - m);
        logit[kk] = e;
        ssum += e;
    }
    const float inv = 1.f / ssum;

    // PV for d = half*8 .. half*8+7
    float o8[8];
    #pragma unroll
    for (int d = 0; d < 8; ++d) o8[d] = 0.f;

    #pragma unroll
    for (int i = 0; i < KS_; ++i) {
        float vr[14];
        const float* vp = &vs[(r0 + i) * LDSTR + w0 + half * 8];
        #pragma unroll
        for (int tt = 0; tt < 12; tt += 4) {
            float4 f = *reinterpret_cast<const float4*>(vp + tt);
            vr[tt] = f.x; vr[tt + 1] = f.y; vr[tt + 2] = f.z; vr[tt + 3] = f.w;
        }
        float2 f2 = *reinterpret_cast<const float2*>(vp + 12);
        vr[12] = f2.x; vr[13] = f2.y;
        #pragma unroll
        for (int j = 0; j < KS_; ++j) {
            float wgt = logit[i * KS_ + j];
            #pragma unroll
            for (int d = 0; d < 8; ++d) o8[d] = fmaf(wgt, vr[d + j], o8[d]);
        }
    }

    float* op = out + (((size_t)b * C_ + c) * H_ + ho) * W_ + w0 + half * 8;
    #pragma unroll
    for (int d = 0; d < 8; d += 4) {
        float4 f;
        f.x = fmaxf(o8[d]     * inv, 0.f);
        f.y = fmaxf(o8[d + 1] * inv, 0.f);
        f.z = fmaxf(o8[d + 2] * inv, 0.f);
        f.w = fmaxf(o8[d + 3] * inv, 0.f);
        *reinterpret_cast<float4*>(op + d) = f;
    }
}

extern "C" void kernel_launch(void* const* d_in, const int* in_sizes, int n_in,
                              void* d_out, int out_size, void* d_ws, size_t ws_size,
                              hipStream_t stream) {
    const float* in   = (const float*)d_in[0];
    const float* qw   = (const float*)d_in[1];
    const float* qb   = (const float*)d_in[2];
    const float* kw   = (const float*)d_in[3];
    const float* kb   = (const float*)d_in[4];
    const float* vw   = (const float*)d_in[5];
    const float* vb   = (const float*)d_in[6];
    const float* relh = (const float*)d_in[7];
    const float* relw = (const float*)d_in[8];
    float* out = (float*)d_out;

    float* wk = (float*)d_ws;
    float* wv = wk + (size_t)B_ * C_ * PH_ * PSTR;
    float* wq = wv + (size_t)B_ * C_ * PH_ * PSTR;

    dim3 cgrid((PH_ * PH_ + 127) / 128, B_, 12);  // 82 x 4 x 12 = 3936 blocks
    qkv_conv_kernel<<<cgrid, 128, 0, stream>>>(in, qw, qb, kw, kb, vw, vb, wq, wk, wv);

    dim3 agrid(B_ * C_ * 3);                      // 768 blocks x 384 threads
    attn_kernel<<<agrid, 384, 0, stream>>>(wq, wk, wv, relh, relw, out);
}

// Round 6
// 41.875 us; speedup vs baseline: 2.3140x; 1.1127x over previous
//
#include <hip/hip_runtime.h>

#define B_ 4
#define C_ 64
#define H_ 96
#define W_ 96
#define KS_ 7
#define PH_ 102      // padded spatial extent
#define PSTR 104     // padded row stride (floats), 16-aligned w0 float4-legal
#define PHW (PH_ * PSTR)
#define NPIX (H_ * W_)   // 9216
#define LDSTR 108    // attn LDS row stride

typedef __attribute__((ext_vector_type(8))) short short8;
typedef __attribute__((ext_vector_type(4))) float f32x4;

static __device__ inline ushort f2bf(float f) {
    union { float f; unsigned u; } v; v.f = f;
    unsigned r = (v.u + 0x7fff + ((v.u >> 16) & 1)) >> 16;   // RNE
    return (ushort)r;
}

// ws layout (floats):
//   k:  [B][C][102][104] = 2715648
//   v:  [B][C][102][104] = 2715648
//   q:  [B][C][96][96]   = 2359296
//   wbf: ushort[192*64] (q,k,v weights bf16)   bias_all: float[192]

// ---- prep: W->bf16, bias stack, k/v border = bias ----
__global__ __launch_bounds__(256) void prep_kernel(
    const float* __restrict__ qw, const float* __restrict__ qb,
    const float* __restrict__ kw, const float* __restrict__ kb,
    const float* __restrict__ vw, const float* __restrict__ vb,
    ushort* __restrict__ wbf, float* __restrict__ bias_all,
    float* __restrict__ outk, float* __restrict__ outv)
{
    const int gid = blockIdx.x * 256 + threadIdx.x;
    if (blockIdx.x < 48) {                       // 12288 weight elems
        const int idx = gid;
        const float* src = (idx < 4096) ? qw : (idx < 8192 ? kw : vw);
        wbf[idx] = f2bf(src[idx & 4095]);
        if (idx < 192) {
            const float* bsrc = (idx < 64) ? qb : (idx < 128 ? kb : vb);
            bias_all[idx] = bsrc[idx & 63];
        }
        return;
    }
    int item = gid - 48 * 256;                   // border fill: 608256 items
    if (item >= B_ * 2 * C_ * 1188) return;
    const int bp   = item % 1188;
    int rest       = item / 1188;
    const int ch   = rest % C_;
    rest /= C_;
    const int mode = rest & 1;                   // 0=k, 1=v
    const int b    = rest >> 1;
    int ph, pw;
    if (bp < 306)      { ph = bp / 102;              pw = bp % 102; }
    else if (bp < 612) { int j = bp - 306; ph = 99 + j / 102; pw = j % 102; }
    else               { int j = bp - 612; ph = 3 + j / 6; int c2 = j % 6;
                         pw = (c2 < 3) ? c2 : 96 + c2 - 3 + 3; }  // 0,1,2 or 99,100,101
    const float bias = (mode ? vb : kb)[ch];
    float* dst = mode ? outv : outk;
    dst[((size_t)b * C_ + ch) * PHW + ph * PSTR + pw] = bias;
}

// ---- MFMA conv: Out[192][64pix] tile per block; 4 waves x (3 M-tiles x 4 N-tiles) ----
__global__ __launch_bounds__(256) void mfma_conv_kernel(
    const float* __restrict__ in,          // [B][64][9216]
    const ushort* __restrict__ wbf,        // [192][64] bf16
    const float* __restrict__ bias_all,    // [192]
    float* __restrict__ outq, float* __restrict__ outk, float* __restrict__ outv)
{
    const int b    = blockIdx.y;
    const int pix0 = blockIdx.x * 64;
    const int t    = threadIdx.x;
    const int lane = t & 63;
    const int wv   = t >> 6;

    __shared__ ushort xs[64 * 64];   // [pix][ch] bf16, byte ^= (pix&7)<<4

    {   // stage X tile: read f32 (coalesced over pix), write transposed bf16
        const int pix = t & 63;
        const int cg  = t >> 6;
        const float* xp = in + (size_t)b * C_ * NPIX + pix0 + pix;
        #pragma unroll
        for (int g = 0; g < 4; ++g) {
            const int ch = (cg + 4 * g) * 4;
            float x0 = xp[(size_t)(ch    ) * NPIX];
            float x1 = xp[(size_t)(ch + 1) * NPIX];
            float x2 = xp[(size_t)(ch + 2) * NPIX];
            float x3 = xp[(size_t)(ch + 3) * NPIX];
            ushort4 u = make_ushort4(f2bf(x0), f2bf(x1), f2bf(x2), f2bf(x3));
            unsigned byte = (unsigned)(pix * 128 + ch * 2) ^ (unsigned)((pix & 7) << 4);
            *reinterpret_cast<ushort4*>(reinterpret_cast<char*>(xs) + byte) = u;
        }
    }
    __syncthreads();

    // A fragments: lane holds W[mt*16 + (lane&15)][ka*32 + (lane>>4)*8 .. +8]
    short8 afr[3][2];
    #pragma unroll
    for (int i = 0; i < 3; ++i) {
        const int row = (3 * wv + i) * 16 + (lane & 15);
        #pragma unroll
        for (int ka = 0; ka < 2; ++ka) {
            const int kk = ka * 32 + (lane >> 4) * 8;
            afr[i][ka] = *reinterpret_cast<const short8*>(wbf + row * 64 + kk);
        }
    }
    // B fragments from swizzled LDS
    short8 bfr[4][2];
    #pragma unroll
    for (int nt = 0; nt < 4; ++nt) {
        const int pl = nt * 16 + (lane & 15);
        #pragma unroll
        for (int ka = 0; ka < 2; ++ka) {
            const int kk = ka * 32 + (lane >> 4) * 8;
            unsigned byte = (unsigned)(pl * 128 + kk * 2) ^ (unsigned)((pl & 7) << 4);
            bfr[nt][ka] = *reinterpret_cast<const short8*>(
                reinterpret_cast<const char*>(xs) + byte);
        }
    }
    // accumulators, bias-initialized (C row = (lane>>4)*4 + reg)
    f32x4 acc[3][4];
    #pragma unroll
    for (int i = 0; i < 3; ++i) {
        const int mt = 3 * wv + i;
        f32x4 bi;
        #pragma unroll
        for (int r = 0; r < 4; ++r) bi[r] = bias_all[mt * 16 + (lane >> 4) * 4 + r];
        #pragma unroll
        for (int nt = 0; nt < 4; ++nt) acc[i][nt] = bi;
    }
    #pragma unroll
    for (int i = 0; i < 3; ++i) {
        #pragma unroll
        for (int nt = 0; nt < 4; ++nt) {
            acc[i][nt] = __builtin_amdgcn_mfma_f32_16x16x32_bf16(
                afr[i][0], bfr[nt][0], acc[i][nt], 0, 0, 0);
            acc[i][nt] = __builtin_amdgcn_mfma_f32_16x16x32_bf16(
                afr[i][1], bfr[nt][1], acc[i][nt], 0, 0, 0);
        }
    }
    // store: lane's column = pixel, 4 consecutive oc per reg
    #pragma unroll
    for (int nt = 0; nt < 4; ++nt) {
        const int pix  = pix0 + nt * 16 + (lane & 15);
        const int h    = pix / 96;
        const int w    = pix - h * 96;
        const int ppix = (h + 3) * PSTR + (w + 3);
        #pragma unroll
        for (int i = 0; i < 3; ++i) {
            const int mt   = 3 * wv + i;
            const int mode = mt >> 2;                       // wave-uniform
            const int ocb  = (mt & 3) * 16 + (lane >> 4) * 4;
            #pragma unroll
            for (int r = 0; r < 4; ++r) {
                const float val = acc[i][nt][r];
                if (mode == 0)
                    outq[((size_t)b * C_ + ocb + r) * NPIX + pix] = val;
                else if (mode == 1)
                    outk[((size_t)b * C_ + ocb + r) * PHW + ppix] = val;
                else
                    outv[((size_t)b * C_ + ocb + r) * PHW + ppix] = val;
            }
        }
    }
}

// ---- attention (unchanged from R5) ----
__global__ __launch_bounds__(384) void attn_kernel(
    const float* __restrict__ q, const float* __restrict__ k,
    const float* __restrict__ v, const float* __restrict__ relh,
    const float* __restrict__ relw, float* __restrict__ out)
{
    const int bx   = blockIdx.x;
    const int tile = bx % 3;
    const int c    = (bx / 3) % C_;
    const int b    = bx / (3 * C_);
    const int ho0  = tile * 32;
    const int t    = threadIdx.x;

    __shared__ float ks[38 * LDSTR];
    __shared__ float vs[38 * LDSTR];
    __shared__ float rel_s[49];

    if (t < 49) {
        const int i = t / KS_, j = t % KS_;
        float s = 0.f;
        #pragma unroll
        for (int cc = 0; cc < C_ / 2; ++cc)
            s += relh[cc * KS_ + i] + relw[cc * KS_ + j];
        rel_s[t] = s;
    }
    {
        const float* kp = k + ((size_t)(b * C_ + c) * PH_ + ho0) * PSTR;
        const float* vp = v + ((size_t)(b * C_ + c) * PH_ + ho0) * PSTR;
        for (int idx = t; idx < 38 * 26; idx += 384) {
            const int r = idx / 26, col = (idx % 26) * 4;
            *reinterpret_cast<float4*>(&ks[r * LDSTR + col]) =
                *reinterpret_cast<const float4*>(kp + r * PSTR + col);
            *reinterpret_cast<float4*>(&vs[r * LDSTR + col]) =
                *reinterpret_cast<const float4*>(vp + r * PSTR + col);
        }
    }
    __syncthreads();

    const int r0   = t / 12;
    const int rest = t % 12;
    const int w0   = (rest >> 1) * 16;
    const int half = rest & 1;
    const int ho   = ho0 + r0;

    const float* qp = q + (((size_t)b * C_ + c) * H_ + ho) * W_ + w0;
    float qs[16];
    #pragma unroll
    for (int tt = 0; tt < 16; tt += 4) {
        float4 f = *reinterpret_cast<const float4*>(qp + tt);
        qs[tt] = f.x; qs[tt + 1] = f.y; qs[tt + 2] = f.z; qs[tt + 3] = f.w;
    }
    float qsum = 0.f;
    #pragma unroll
    for (int tt = 0; tt < 16; ++tt) qsum += qs[tt];

    float logit[49];
    #pragma unroll
    for (int i = 0; i < KS_; ++i) {
        float kr[22];
        const float* kp = &ks[(r0 + i) * LDSTR + w0];
        #pragma unroll
        for (int tt = 0; tt < 20; tt += 4) {
            float4 f = *reinterpret_cast<const float4*>(kp + tt);
            kr[tt] = f.x; kr[tt + 1] = f.y; kr[tt + 2] = f.z; kr[tt + 3] = f.w;
        }
        float2 f2 = *reinterpret_cast<const float2*>(kp + 20);
        kr[20] = f2.x; kr[21] = f2.y;
        #pragma unroll
        for (int j = 0; j < KS_; ++j) {
            float s = 0.f;
            #pragma unroll
            for (int tt = 0; tt < 16; ++tt) s = fmaf(qs[tt], kr[tt + j], s);
            logit[i * KS_ + j] = s + qsum * rel_s[i * KS_ + j];
        }
    }

    float m = -1e30f;
    #pragma unroll
    for (int kk = 0; kk < 49; ++kk) m = fmaxf(m, logit[kk]);
    float ssum = 0.f;
    #pragma unroll
    for (int kk = 0; kk < 49; ++kk) {
        float e = __expf(logit[kk] - m);
        logit[kk] = e;
        ssum += e;
    }
    const float inv = 1.f / ssum;

    float o8[8];
    #pragma unroll
    for (int d = 0; d < 8; ++d) o8[d] = 0.f;

    #pragma unroll
    for (int i = 0; i < KS_; ++i) {
        float vr[14];
        const float* vp = &vs[(r0 + i) * LDSTR + w0 + half * 8];
        #pragma unroll
        for (int tt = 0; tt < 12; tt += 4) {
            float4 f = *reinterpret_cast<const float4*>(vp + tt);
            vr[tt] = f.x; vr[tt + 1] = f.y; vr[tt + 2] = f.z; vr[tt + 3] = f.w;
        }
        float2 f2 = *reinterpret_cast<const float2*>(vp + 12);
        vr[12] = f2.x; vr[13] = f2.y;
        #pragma unroll
        for (int j = 0; j < KS_; ++j) {
            float wgt = logit[i * KS_ + j];
            #pragma unroll
            for (int d = 0; d < 8; ++d) o8[d] = fmaf(wgt, vr[d + j], o8[d]);
        }
    }

    float* op = out + (((size_t)b * C_ + c) * H_ + ho) * W_ + w0 + half * 8;
    #pragma unroll
    for (int d = 0; d < 8; d += 4) {
        float4 f;
        f.x = fmaxf(o8[d]     * inv, 0.f);
        f.y = fmaxf(o8[d + 1] * inv, 0.f);
        f.z = fmaxf(o8[d + 2] * inv, 0.f);
        f.w = fmaxf(o8[d + 3] * inv, 0.f);
        *reinterpret_cast<float4*>(op + d) = f;
    }
}

extern "C" void kernel_launch(void* const* d_in, const int* in_sizes, int n_in,
                              void* d_out, int out_size, void* d_ws, size_t ws_size,
                              hipStream_t stream) {
    const float* in   = (const float*)d_in[0];
    const float* qw   = (const float*)d_in[1];
    const float* qb   = (const float*)d_in[2];
    const float* kw   = (const float*)d_in[3];
    const float* kb   = (const float*)d_in[4];
    const float* vw   = (const float*)d_in[5];
    const float* vb   = (const float*)d_in[6];
    const float* relh = (const float*)d_in[7];
    const float* relw = (const float*)d_in[8];
    float* out = (float*)d_out;

    float*  wk  = (float*)d_ws;
    float*  wvv = wk  + (size_t)B_ * C_ * PHW;
    float*  wq  = wvv + (size_t)B_ * C_ * PHW;
    ushort* wbf = (ushort*)(wq + (size_t)B_ * C_ * NPIX);
    float*  wbias = (float*)(wbf + 192 * 64);

    // prep: 48 W-convert blocks + 2376 border-fill blocks
    prep_kernel<<<48 + 2376, 256, 0, stream>>>(qw, qb, kw, kb, vw, vb,
                                               wbf, wbias, wk, wvv);

    dim3 cgrid(NPIX / 64, B_);   // 144 x 4 blocks
    mfma_conv_kernel<<<cgrid, 256, 0, stream>>>(in, wbf, wbias, wq, wk, wvv);

    dim3 agrid(B_ * C_ * 3);     // 768 blocks x 384 threads
    attn_kernel<<<agrid, 384, 0, stream>>>(wq, wk, wvv, relh, relw, out);
}